// Round 3
// baseline (347.988 us; speedup 1.0000x reference)
//
#include <hip/hip_runtime.h>
#include <math.h>

// (B,H,W,T,C) = (4,200,200,5,64), fp32 in/out.
constexpr int Bn = 4, Hn = 200, Wn = 200, Tn = 5, Cn = 64;
constexpr int C4 = Cn / 4;                   // 16 float4 per (pixel,t)
constexpr int PPB = 16;                      // pixels per block (2 rows x 8 cols)
constexpr int BR = 2, BC = 8;                // block pixel tile: 2 x 8
constexpr int BLOCK = PPB * C4;              // 256 threads
constexpr int PIX_STRIDE4 = Tn * C4;         // 80 float4 per pixel block
constexpr int STRIPS = Wn / BC;              // 25 column strips per image
constexpr int BROWS  = Hn / BR;              // 100 block-rows per strip
constexpr int BLK_PER_IMG = STRIPS * BROWS;  // 2500
constexpr int NBLK = Bn * BLK_PER_IMG;       // 10,000 blocks
constexpr int NXCD = 8;
constexpr int CHUNK = NBLK / NXCD;           // 1250 (10000 % 8 == 0 -> bijective)

// Native clang vector type — required by __builtin_nontemporal_* (HIP's
// float4 is a class and is rejected). Same 16-B layout/alignment.
typedef float f4 __attribute__((ext_vector_type(4)));

__global__ __launch_bounds__(BLOCK) void tf_warp_kernel(
    const f4* __restrict__ in4,
    const float* __restrict__ ego,
    f4* __restrict__ out4)
{
    __shared__ int   s_base[PPB][4];   // f4-index of corner (y,x) pixel block
    __shared__ float s_wgt[PPB][4];    // bilinear weights with validity folded

    // XCD-aware swizzle: each XCD owns a contiguous range of block IDs.
    const int raw = blockIdx.x;
    const int bid = (raw % NXCD) * CHUNK + raw / NXCD;

    // Column-strip-major 2D tiling: consecutive bids walk DOWN an 8-px-wide
    // strip (2 rows at a time). y-corner reuse distance becomes 1 block
    // (L1-distance) instead of 12.5 blocks across a near-capacity L2, and the
    // per-XCD in-flight input working set shrinks from ~20 full-width rows
    // (~4.3 MB, thrashing the 4 MB L2) to ~2 strips (~2 MB, L2-resident).
    const int b     = bid / BLK_PER_IMG;
    const int r     = bid % BLK_PER_IMG;
    const int strip = r / BROWS;
    const int brow  = r % BROWS;
    const int h0 = brow * BR;
    const int w0 = strip * BC;

    const int tid = threadIdx.x;

    if (tid < PPB) {
        int h = h0 + (tid >> 3);       // 2 rows
        int w = w0 + (tid & 7);        // 8 cols

        float dxn  = ego[b * 3 + 0] * 0.01f;   // / (MAP_RANGE/2 = 100)
        float dyn  = ego[b * 3 + 1] * 0.01f;
        float dyaw = ego[b * 3 + 2];
        float sth, cth;
        sincosf(dyaw, &sth, &cth);
        float tx = -(cth * dxn + sth * dyn);
        float ty =  sth * dxn - cth * dyn;

        float xs = (2.0f * (float)w + 1.0f) / (float)Wn - 1.0f;
        float ys = (2.0f * (float)h + 1.0f) / (float)Hn - 1.0f;

        float gx =  cth * xs + sth * ys + tx;
        float gy = -sth * xs + cth * ys + ty;

        float ix = ((gx + 1.0f) * (float)Wn - 1.0f) * 0.5f;
        float iy = ((gy + 1.0f) * (float)Hn - 1.0f) * 0.5f;

        float ix0f = floorf(ix), iy0f = floorf(iy);
        float wx1 = ix - ix0f, wx0 = 1.0f - wx1;
        float wy1 = iy - iy0f, wy0 = 1.0f - wy1;
        float ix1f = ix0f + 1.0f, iy1f = iy0f + 1.0f;

        bool vx0 = (ix0f >= 0.0f) && (ix0f <= (float)(Wn - 1));
        bool vx1 = (ix1f >= 0.0f) && (ix1f <= (float)(Wn - 1));
        bool vy0 = (iy0f >= 0.0f) && (iy0f <= (float)(Hn - 1));
        bool vy1 = (iy1f >= 0.0f) && (iy1f <= (float)(Hn - 1));

        int x0 = (int)fminf(fmaxf(ix0f, 0.0f), (float)(Wn - 1));
        int x1 = (int)fminf(fmaxf(ix1f, 0.0f), (float)(Wn - 1));
        int y0 = (int)fminf(fmaxf(iy0f, 0.0f), (float)(Hn - 1));
        int y1 = (int)fminf(fmaxf(iy1f, 0.0f), (float)(Hn - 1));

        int bH = b * Hn;
        s_base[tid][0] = ((bH + y0) * Wn + x0) * PIX_STRIDE4;
        s_base[tid][1] = ((bH + y0) * Wn + x1) * PIX_STRIDE4;
        s_base[tid][2] = ((bH + y1) * Wn + x0) * PIX_STRIDE4;
        s_base[tid][3] = ((bH + y1) * Wn + x1) * PIX_STRIDE4;
        s_wgt[tid][0]  = wy0 * wx0 * ((vy0 && vx0) ? 1.0f : 0.0f);
        s_wgt[tid][1]  = wy0 * wx1 * ((vy0 && vx1) ? 1.0f : 0.0f);
        s_wgt[tid][2]  = wy1 * wx0 * ((vy1 && vx0) ? 1.0f : 0.0f);
        s_wgt[tid][3]  = wy1 * wx1 * ((vy1 && vx1) ? 1.0f : 0.0f);
    }
    __syncthreads();

    const int p   = tid >> 4;          // local pixel 0..15
    const int c4  = tid & (C4 - 1);    // f4 lane within channel row
    const int h   = h0 + (p >> 3);
    const int w   = w0 + (p & 7);
    const int pos = (b * Hn + h) * Wn + w;
    const int obase = pos * PIX_STRIDE4 + c4;

    const int b00 = s_base[p][0] + c4;
    const int b01 = s_base[p][1] + c4;
    const int b10 = s_base[p][2] + c4;
    const int b11 = s_base[p][3] + c4;
    const float w00 = s_wgt[p][0];
    const float w01 = s_wgt[p][1];
    const float w10 = s_wgt[p][2];
    const float w11 = s_wgt[p][3];

    // Issue all 17 independent loads up front for max MLP.
    f4 v00[4], v01[4], v10[4], v11[4];
#pragma unroll
    for (int t = 0; t < 4; ++t) {
        v00[t] = in4[b00 + t * C4];
        v01[t] = in4[b01 + t * C4];
        v10[t] = in4[b10 + t * C4];
        v11[t] = in4[b11 + t * C4];
    }
    // Current frame (t = T-1) is read exactly once and never gathered: NT load.
    f4 cur = __builtin_nontemporal_load(&in4[obase + 4 * C4]);

#pragma unroll
    for (int t = 0; t < 4; ++t) {
        f4 o = w00 * v00[t] + w01 * v01[t] + w10 * v10[t] + w11 * v11[t];
        // Output is write-once / never re-read: NT store keeps the per-XCD L2
        // free for the gather-input working set (the MALL is memory-side and
        // can't be protected, but L2 can).
        __builtin_nontemporal_store(o, &out4[obase + t * C4]);
    }
    __builtin_nontemporal_store(cur, &out4[obase + 4 * C4]);
}

extern "C" void kernel_launch(void* const* d_in, const int* in_sizes, int n_in,
                              void* d_out, int out_size, void* d_ws, size_t ws_size,
                              hipStream_t stream) {
    const f4* in4 = (const f4*)d_in[0];
    const float* ego = (const float*)d_in[1];
    f4* out4 = (f4*)d_out;

    tf_warp_kernel<<<NBLK, BLOCK, 0, stream>>>(in4, ego, out4);
}